// Round 10
// baseline (418.917 us; speedup 1.0000x reference)
//
#include <hip/hip_runtime.h>
#include <hip/hip_bf16.h>

#define BB 128
#define TT 512
#define EE 128
#define HH 256
#define MM 1024
#define CC 5

typedef _Float16 h2 __attribute__((ext_vector_type(2)));
typedef __fp16 f16x2 __attribute__((ext_vector_type(2)));
typedef __fp16 f16x8 __attribute__((ext_vector_type(8)));
typedef float  f32x4 __attribute__((ext_vector_type(4)));

__device__ inline h2 mkh2(float a, float b) {
    return __builtin_bit_cast(h2, __builtin_amdgcn_cvt_pkrtz(a, b));
}

// pack 8 f32 -> 8 f16 (one MFMA operand fragment)
__device__ inline f16x8 pack8(float4 lo, float4 hi) {
    union { f16x2 h[4]; f16x8 v; } u;
    u.h[0] = __builtin_amdgcn_cvt_pkrtz(lo.x, lo.y);
    u.h[1] = __builtin_amdgcn_cvt_pkrtz(lo.z, lo.w);
    u.h[2] = __builtin_amdgcn_cvt_pkrtz(hi.x, hi.y);
    u.h[3] = __builtin_amdgcn_cvt_pkrtz(hi.z, hi.w);
    return u.v;
}

__device__ inline float dot2f(h2 a, h2 b, float c) {
#if __has_builtin(__builtin_amdgcn_fdot2)
    return __builtin_amdgcn_fdot2(a, b, c, false);
#else
    return c + (float)a.x * (float)b.x + (float)a.y * (float)b.y;
#endif
}

// Quad butterfly sum via DPP (VALU pipe, no LDS traffic).
__device__ inline float dpp_add4(float x) {
    int t = __builtin_amdgcn_update_dpp(0, __builtin_bit_cast(int, x), 0xB1, 0xF, 0xF, true);
    x += __builtin_bit_cast(float, t);
    t = __builtin_amdgcn_update_dpp(0, __builtin_bit_cast(int, x), 0x4E, 0xF, 0xF, true);
    x += __builtin_bit_cast(float, t);
    return x;
}

__device__ inline float fast_tanh(float x) {
    float e = __expf(2.0f * x);
    return 1.0f - 2.0f / (e + 1.0f);
}

// ---------------------------------------------------------------------------
// K (R16): producer/consumer fused kernel. 512 threads, 1 WG per batch elt.
//  - waves 0-3 (tid<256): the VERIFIED R14 serial scan, byte-for-byte
//    (split-K(4)+DPP, uv prefetch, lgkm-only barrier; ~255us standalone).
//  - waves 4-7 (tid>=256): producer — computes chunk c+1's u into the
//    other ubuf half WHILE chunk c is being scanned. Pipelined over the
//    first 3 steps of the chunk: s0 issue global loads (token+emb) into
//    regs; s1 pack8 -> ldsA; s2 MFMA -> ubuf_next. MFMA + VMEM don't
//    contend with the scan's VALU/LDS (m114) -> R14's ~33us serial GEMM
//    phase hidden.
// BARRIER DISCIPLINE: both paths execute exactly 2 + sum(steps_c) barriers
// (steps_c block-uniform). Deadlock-free by construction.
// MFMA layouts (m89/m120-verified): A[m=lane&15][k=quad*8+j],
// B[k=quad*8+j][n=lane&15], D col=lane&15 row=quad*4+reg.
// ---------------------------------------------------------------------------
__global__ __launch_bounds__(512, 1)
void k_fused(const int* __restrict__ x, const int* __restrict__ lengths,
             const float* __restrict__ emb,
             const float* __restrict__ W_ih, const float* __restrict__ W_hh,
             const float* __restrict__ b_ih, const float* __restrict__ b_hh,
             const float* __restrict__ W0, const float* __restrict__ b0,
             const float* __restrict__ W1, const float* __restrict__ b1,
             float* __restrict__ out)
{
    const int b   = blockIdx.x;
    const int tid = threadIdx.x;                  // 0..511
    const int len = lengths[b];
    const int len2 = (len + 1) & ~1;              // even-rounded (<= TT)
    const int start = TT - len;                   // first active t
    const int nc = (len2 + 63) >> 6;              // number of 64-step chunks

    __shared__ __align__(16) char hbufA[512];       // 256 f16 (b128-read)
    __shared__ __align__(16) char hbufB[512];
    __shared__ __align__(16) char ubufA[64 * 512];  // 32KB u chunk (even)
    __shared__ __align__(16) char ubufB[64 * 512];  // 32KB u chunk (odd)
    __shared__ __align__(16) char ldsA[64 * 256];   // 16KB f16 emb A-stage
    __shared__ __align__(16) float sh[HH];          // head: h row (f32)
    __shared__ __align__(16) float sh1[MM];         // head: relu(h@W0^T+b0)
    __shared__ float sred[CC][8];
    __shared__ float slog[CC];

    if (tid < 128) {
        ((float*)hbufA)[tid] = 0.f;
        ((float*)hbufB)[tid] = 0.f;
    }

#define SBAR {                                                               \
        __builtin_amdgcn_sched_barrier(0);                                   \
        asm volatile("s_waitcnt lgkmcnt(0)");                                \
        __builtin_amdgcn_s_barrier();                                        \
        __builtin_amdgcn_sched_barrier(0);                                   \
    }

    if (tid < 256) {
        // =================== SCAN PATH (verified R14) ===================
        const int kc = tid & 3;
        const int g  = tid >> 2;

        h2 w[4][32];
        #pragma unroll
        for (int m = 0; m < 4; ++m) {
            const float4* wr = (const float4*)(W_hh + (size_t)(4*g + m) * HH + kc*64);
            #pragma unroll
            for (int q = 0; q < 16; ++q) {
                float4 v = wr[q];
                w[m][2*q]   = mkh2(v.x, v.y);
                w[m][2*q+1] = mkh2(v.z, v.w);
            }
        }
        const int wr_off = (tid >> 6) * 128
                         + (((((tid >> 3) & 7) + 2 * (tid >> 6)) & 7) << 4)
                         + ((tid & 7) << 1);
        int roff[8];
        #pragma unroll
        for (int i = 0; i < 8; ++i)
            roff[i] = kc * 128 + (((i + 2 * kc) & 7) << 4);

        SBAR;                                       // matches producer stage
        SBAR;                                       // matches producer compute
        float hlast = 0.f;

#define SSTEP(HSRC, HDST, UVC, UVN, S_, UB) {                                \
        UVN = *(const _Float16*)((UB) + ((((S_) + 1) & 63) << 9) + tid * 2); \
        float a0 = 0.f, a1 = 0.f, a2 = 0.f, a3 = 0.f;                        \
        _Pragma("unroll")                                                    \
        for (int i = 0; i < 8; ++i) {                                        \
            float4 hv = *(const float4*)(HSRC + roff[i]);                    \
            h2* hp = (h2*)&hv;                                               \
            _Pragma("unroll")                                                \
            for (int z = 0; z < 4; ++z) {                                    \
                a0 = dot2f(w[0][4*i+z], hp[z], a0);                          \
                a1 = dot2f(w[1][4*i+z], hp[z], a1);                          \
                a2 = dot2f(w[2][4*i+z], hp[z], a2);                          \
                a3 = dot2f(w[3][4*i+z], hp[z], a3);                          \
            }                                                                \
        }                                                                    \
        a0 = dpp_add4(a0); a1 = dpp_add4(a1);                                \
        a2 = dpp_add4(a2); a3 = dpp_add4(a3);                                \
        float v = (kc == 0) ? a0 : (kc == 1) ? a1 : (kc == 2) ? a2 : a3;     \
        const float hnew = fast_tanh(v + (float)UVC);                        \
        hlast = hnew;                                                        \
        *(_Float16*)(HDST + wr_off) = (_Float16)hnew;                        \
        SBAR;                                                                \
    }

        for (int c = 0; c < nc; ++c) {
            const char* ub = (c & 1) ? ubufB : ubufA;
            const int steps = (len2 - c * 64 < 64) ? (len2 - c * 64) : 64;
            _Float16 uv0 = *(const _Float16*)(ub + tid * 2);
            _Float16 uv1;
            for (int s = 0; s < steps; s += 2) {
                SSTEP(hbufA, hbufB, uv0, uv1, s,     ub);   // even: A -> B
                SSTEP(hbufB, hbufA, uv1, uv0, s + 1, ub);   // odd:  B -> A
            }
        }
        sh[tid] = hlast;
    } else {
        // =================== PRODUCER PATH ===================
        const int ptid = tid - 256;                // 0..255
        const int wv   = ptid >> 6;                // wave 0..3
        const int lane = ptid & 63;
        const int l15  = lane & 15;
        const int quad = lane >> 4;

        // W_ih B-frags (verified R14 layout): n = 64*wv + 16*ct + l15
        f16x8 bfih[4][4];
        float bias[4];
        #pragma unroll
        for (int ct = 0; ct < 4; ++ct) {
            const int n = 64 * wv + 16 * ct + l15;
            const float* wp = W_ih + (size_t)n * EE;
            #pragma unroll
            for (int kk = 0; kk < 4; ++kk) {
                const float4* p = (const float4*)(wp + 32 * kk + 8 * quad);
                bfih[ct][kk] = pack8(p[0], p[1]);
            }
            bias[ct] = b_ih[n] + b_hh[n];
        }

        float4 stash[8];                           // staged emb rows (regs)

#define PLOADS(TBASE_) {                                                     \
        _Pragma("unroll")                                                    \
        for (int half = 0; half < 2; ++half) {                               \
            const int r = (ptid >> 3) + 32 * half;                           \
            const int sg = ptid & 7;                                         \
            int tg = (TBASE_) + r;                                           \
            tg = (tg < TT - 1) ? tg : (TT - 1);                              \
            const int tok = x[(size_t)b * TT + tg];                          \
            const float4* ep = (const float4*)(emb + (size_t)tok * EE + 16 * sg); \
            stash[4*half+0] = ep[0]; stash[4*half+1] = ep[1];                \
            stash[4*half+2] = ep[2]; stash[4*half+3] = ep[3];                \
        }                                                                    \
    }

#define PWRITES {                                                            \
        _Pragma("unroll")                                                    \
        for (int half = 0; half < 2; ++half) {                               \
            const int r = (ptid >> 3) + 32 * half;                           \
            const int sg = ptid & 7;                                         \
            *(f16x8*)(ldsA + r * 256 + 32 * sg)                              \
                = pack8(stash[4*half+0], stash[4*half+1]);                   \
            *(f16x8*)(ldsA + r * 256 + 32 * sg + 16)                         \
                = pack8(stash[4*half+2], stash[4*half+3]);                   \
        }                                                                    \
    }

#define PCOMPUTE(UBN_, TBASE_) {                                             \
        f32x4 acc[4][4];                                                     \
        _Pragma("unroll")                                                    \
        for (int rt = 0; rt < 4; ++rt)                                       \
            _Pragma("unroll")                                                \
            for (int ct = 0; ct < 4; ++ct)                                   \
                acc[rt][ct] = (f32x4){bias[ct], bias[ct], bias[ct], bias[ct]};\
        _Pragma("unroll")                                                    \
        for (int kk = 0; kk < 4; ++kk) {                                     \
            const int ko = (32 * kk + 8 * quad) * 2;                         \
            f16x8 af0 = *(const f16x8*)(ldsA + (l15)      * 256 + ko);       \
            f16x8 af1 = *(const f16x8*)(ldsA + (16 + l15) * 256 + ko);       \
            f16x8 af2 = *(const f16x8*)(ldsA + (32 + l15) * 256 + ko);       \
            f16x8 af3 = *(const f16x8*)(ldsA + (48 + l15) * 256 + ko);       \
            _Pragma("unroll")                                                \
            for (int ct = 0; ct < 4; ++ct) {                                 \
                acc[0][ct] = __builtin_amdgcn_mfma_f32_16x16x32_f16(af0, bfih[ct][kk], acc[0][ct], 0, 0, 0); \
                acc[1][ct] = __builtin_amdgcn_mfma_f32_16x16x32_f16(af1, bfih[ct][kk], acc[1][ct], 0, 0, 0); \
                acc[2][ct] = __builtin_amdgcn_mfma_f32_16x16x32_f16(af2, bfih[ct][kk], acc[2][ct], 0, 0, 0); \
                acc[3][ct] = __builtin_amdgcn_mfma_f32_16x16x32_f16(af3, bfih[ct][kk], acc[3][ct], 0, 0, 0); \
            }                                                                \
        }                                                                    \
        _Pragma("unroll")                                                    \
        for (int rt = 0; rt < 4; ++rt) {                                     \
            _Pragma("unroll")                                                \
            for (int ct = 0; ct < 4; ++ct) {                                 \
                const int chb = (64 * wv + 16 * ct + l15) * 2;               \
                _Pragma("unroll")                                            \
                for (int rg = 0; rg < 4; ++rg) {                             \
                    const int tok = 16 * rt + 4 * quad + rg;                 \
                    const bool act = ((TBASE_) + tok) >= start;              \
                    const float dv = act ? acc[rt][ct][rg] : 0.f;            \
                    *(_Float16*)((UBN_) + tok * 512 + chb) = (_Float16)dv;   \
                }                                                            \
            }                                                                \
        }                                                                    \
    }

        // pre-phase: produce chunk 0 into ubufA (2 barriers, matched by scan)
        const int tbase0 = TT - len2;
        if (nc > 0) { PLOADS(tbase0); PWRITES; }
        SBAR;
        if (nc > 0) { PCOMPUTE(ubufA, tbase0); }
        SBAR;

        // main loop: during chunk c's steps, produce chunk c+1
        for (int c = 0; c < nc; ++c) {
            const int steps = (len2 - c * 64 < 64) ? (len2 - c * 64) : 64;
            char* ubn = (c & 1) ? ubufA : ubufB;   // buffer for chunk c+1
            const int tbn = (TT - len2) + 64 * (c + 1);
            const bool prod = (c + 1 < nc);
            for (int s = 0; s < steps; ++s) {
                if (prod) {
                    if (s == 0)      { PLOADS(tbn); }
                    else if (s == 1) { PWRITES; }
                    else if (s == 2) { PCOMPUTE(ubn, tbn); }
                }
                SBAR;
            }
        }
    }
    __syncthreads();

    // ---- fused MLP head + log_softmax (512 threads, verified R15) ----
    float acc[2];
    #pragma unroll
    for (int i = 0; i < 2; ++i) acc[i] = b0[tid + 512 * i];
    const float4* sh4 = (const float4*)sh;
    for (int k4 = 0; k4 < HH / 4; ++k4) {
        float4 hv = sh4[k4];
        #pragma unroll
        for (int i = 0; i < 2; ++i) {
            float4 wv4 = ((const float4*)(W0 + (size_t)(tid + 512 * i) * HH))[k4];
            acc[i] += wv4.x * hv.x + wv4.y * hv.y + wv4.z * hv.z + wv4.w * hv.w;
        }
    }
    #pragma unroll
    for (int i = 0; i < 2; ++i) sh1[tid + 512 * i] = fmaxf(acc[i], 0.f);
    __syncthreads();

    float pc[CC] = {0.f, 0.f, 0.f, 0.f, 0.f};
    #pragma unroll
    for (int i = 0; i < 2; ++i) {
        const int k = tid + 512 * i;
        float hv = sh1[k];
        #pragma unroll
        for (int c = 0; c < CC; ++c) pc[c] += W1[(size_t)c * MM + k] * hv;
    }
    const int lane6 = tid & 63, wid = tid >> 6;
    #pragma unroll
    for (int c = 0; c < CC; ++c) {
        float v = pc[c];
        #pragma unroll
        for (int off = 32; off > 0; off >>= 1) v += __shfl_down(v, off, 64);
        if (lane6 == 0) sred[c][wid] = v;
    }
    __syncthreads();
    if (tid < CC) {
        float s = b1[tid];
        #pragma unroll
        for (int q = 0; q < 8; ++q) s += sred[tid][q];
        slog[tid] = fmaxf(s, 0.f);
    }
    __syncthreads();
    if (tid < CC) {
        float mx = slog[0];
        #pragma unroll
        for (int c = 1; c < CC; ++c) mx = fmaxf(mx, slog[c]);
        float se = 0.f;
        #pragma unroll
        for (int c = 0; c < CC; ++c) se += __expf(slog[c] - mx);
        out[(size_t)b * CC + tid] = slog[tid] - mx - __logf(se);
    }
}

// ---------------------------------------------------------------------------
extern "C" void kernel_launch(void* const* d_in, const int* in_sizes, int n_in,
                              void* d_out, int out_size, void* d_ws, size_t ws_size,
                              hipStream_t stream) {
    const int*   x       = (const int*)d_in[0];
    const int*   lengths = (const int*)d_in[1];
    const float* emb     = (const float*)d_in[2];
    const float* W_ih    = (const float*)d_in[3];
    const float* W_hh    = (const float*)d_in[4];
    const float* b_ih    = (const float*)d_in[5];
    const float* b_hh    = (const float*)d_in[6];
    const float* W0      = (const float*)d_in[7];
    const float* b0      = (const float*)d_in[8];
    const float* W1      = (const float*)d_in[9];
    const float* b1      = (const float*)d_in[10];
    float* out = (float*)d_out;

    // workspace unused (u eliminated)
    (void)d_ws; (void)ws_size;

    k_fused<<<BB, 512, 0, stream>>>(x, lengths, emb, W_ih, W_hh,
                                    b_ih, b_hh, W0, b0, W1, b1, out);
}

// Round 11
// 376.773 us; speedup vs baseline: 1.1119x; 1.1119x over previous
//
#include <hip/hip_runtime.h>
#include <hip/hip_bf16.h>

#define BB 128
#define TT 512
#define EE 128
#define HH 256
#define MM 1024
#define CC 5

typedef _Float16 h2 __attribute__((ext_vector_type(2)));
typedef __fp16 f16x2 __attribute__((ext_vector_type(2)));
typedef __fp16 f16x8 __attribute__((ext_vector_type(8)));
typedef float  f32x4 __attribute__((ext_vector_type(4)));

__device__ inline h2 mkh2(float a, float b) {
    return __builtin_bit_cast(h2, __builtin_amdgcn_cvt_pkrtz(a, b));
}

// pack 8 f32 -> 8 f16 (one MFMA operand fragment)
__device__ inline f16x8 pack8(float4 lo, float4 hi) {
    union { f16x2 h[4]; f16x8 v; } u;
    u.h[0] = __builtin_amdgcn_cvt_pkrtz(lo.x, lo.y);
    u.h[1] = __builtin_amdgcn_cvt_pkrtz(lo.z, lo.w);
    u.h[2] = __builtin_amdgcn_cvt_pkrtz(hi.x, hi.y);
    u.h[3] = __builtin_amdgcn_cvt_pkrtz(hi.z, hi.w);
    return u.v;
}

__device__ inline float dot2f(h2 a, h2 b, float c) {
#if __has_builtin(__builtin_amdgcn_fdot2)
    return __builtin_amdgcn_fdot2(a, b, c, false);
#else
    return c + (float)a.x * (float)b.x + (float)a.y * (float)b.y;
#endif
}

// Quad butterfly sum via DPP (VALU pipe, no LDS traffic).
__device__ inline float dpp_add4(float x) {
    int t = __builtin_amdgcn_update_dpp(0, __builtin_bit_cast(int, x), 0xB1, 0xF, 0xF, true);
    x += __builtin_bit_cast(float, t);
    t = __builtin_amdgcn_update_dpp(0, __builtin_bit_cast(int, x), 0x4E, 0xF, 0xF, true);
    x += __builtin_bit_cast(float, t);
    return x;
}

__device__ inline float fast_tanh(float x) {
    float e = __expf(2.0f * x);
    return 1.0f - 2.0f / (e + 1.0f);
}

// ---------------------------------------------------------------------------
// K (R17): R14 (best verified: 288us kernel / 383 total) + chunk-gather
// prefetch. One WG (256 thr = 4 waves, 1/SIMD) per batch element.
// Per 64-step chunk:
//   PWRITES: stash (prefetched regs) -> f16 ldsA  [gather ALREADY done]
//   sync; PCOMPUTE: MFMA (W_ih frags resident) -> ubuf, masked; sync
//   scan 64 steps (verified R14 SSTEP); BEFORE step 0, issue next chunk's
//   token+emb global loads into stash[8] regs — SBAR waits lgkmcnt only,
//   so these VMEM loads stay in flight under the whole chunk's scan and
//   the ~2.5us serial gather latency per boundary disappears.
// Single ubuf: chunk c+1's PCOMPUTE runs only after chunk c is consumed.
// MFMA layouts (m89/m120-verified): A[m=lane&15][k=quad*8+j],
// B[k=quad*8+j][n=lane&15], D col=lane&15 row=quad*4+reg.
// ---------------------------------------------------------------------------
__global__ __launch_bounds__(256, 1)
void k_fused(const int* __restrict__ x, const int* __restrict__ lengths,
             const float* __restrict__ emb,
             const float* __restrict__ W_ih, const float* __restrict__ W_hh,
             const float* __restrict__ b_ih, const float* __restrict__ b_hh,
             const float* __restrict__ W0, const float* __restrict__ b0,
             const float* __restrict__ W1, const float* __restrict__ b1,
             float* __restrict__ out)
{
    const int b   = blockIdx.x;
    const int tid = threadIdx.x;
    const int kc  = tid & 3;
    const int g   = tid >> 2;
    const int wv   = tid >> 6;
    const int lane = tid & 63;
    const int l15  = lane & 15;
    const int quad = lane >> 4;
    const int len  = lengths[b];
    const int len2 = (len + 1) & ~1;              // even-rounded (<= TT)
    const int start = TT - len;                   // first active t
    const int nc = (len2 + 63) >> 6;              // 64-step chunks

    // ---- resident weights ----
    h2 w[4][32];
    #pragma unroll
    for (int m = 0; m < 4; ++m) {
        const float4* wr = (const float4*)(W_hh + (size_t)(4*g + m) * HH + kc*64);
        #pragma unroll
        for (int q = 0; q < 16; ++q) {
            float4 v = wr[q];
            w[m][2*q]   = mkh2(v.x, v.y);
            w[m][2*q+1] = mkh2(v.z, v.w);
        }
    }
    f16x8 bfih[4][4];
    float bias[4];
    #pragma unroll
    for (int ct = 0; ct < 4; ++ct) {
        const int n = 64 * wv + 16 * ct + l15;
        const float* wp = W_ih + (size_t)n * EE;
        #pragma unroll
        for (int kk = 0; kk < 4; ++kk) {
            const float4* p = (const float4*)(wp + 32 * kk + 8 * quad);
            bfih[ct][kk] = pack8(p[0], p[1]);
        }
        bias[ct] = b_ih[n] + b_hh[n];
    }

    __shared__ __align__(16) char hbufA[512];       // 256 f16 (b128-read)
    __shared__ __align__(16) char hbufB[512];
    __shared__ __align__(16) char ubuf[64 * 512];   // 64 steps x 256ch x 2B
    __shared__ __align__(16) char ldsA[64 * 256];   // 16KB f16 emb A-stage
    __shared__ __align__(16) float sh[HH];          // head: h row (f32)
    __shared__ __align__(16) float sh1[MM];         // head: relu(h@W0^T+b0)
    __shared__ float sred[CC][4];
    __shared__ float slog[CC];

    ((float*)hbufA)[tid & 127] = 0.f;               // 512B = 128 floats
    if (tid < 128) ((float*)hbufB)[tid] = 0.f;

    const int wr_off = (tid >> 6) * 128
                     + (((((tid >> 3) & 7) + 2 * (tid >> 6)) & 7) << 4)
                     + ((tid & 7) << 1);
    int roff[8];
    #pragma unroll
    for (int i = 0; i < 8; ++i)
        roff[i] = kc * 128 + (((i + 2 * kc) & 7) << 4);

    __syncthreads();

    float hlast = 0.f;
    float4 stash[8];                                 // prefetched emb rows

#define PLOADS(TBASE_) {                                                     \
        _Pragma("unroll")                                                    \
        for (int half = 0; half < 2; ++half) {                               \
            const int r = (tid >> 3) + 32 * half;                            \
            const int sg = tid & 7;                                          \
            int tg = (TBASE_) + r;                                           \
            tg = (tg < TT - 1) ? tg : (TT - 1);                              \
            tg = (tg < 0) ? 0 : tg;                                          \
            const int tok = x[(size_t)b * TT + tg];                          \
            const float4* ep = (const float4*)(emb + (size_t)tok * EE + 16 * sg); \
            stash[4*half+0] = ep[0]; stash[4*half+1] = ep[1];                \
            stash[4*half+2] = ep[2]; stash[4*half+3] = ep[3];                \
        }                                                                    \
    }

#define PWRITES {                                                            \
        _Pragma("unroll")                                                    \
        for (int half = 0; half < 2; ++half) {                               \
            const int r = (tid >> 3) + 32 * half;                            \
            const int sg = tid & 7;                                          \
            *(f16x8*)(ldsA + r * 256 + 32 * sg)                              \
                = pack8(stash[4*half+0], stash[4*half+1]);                   \
            *(f16x8*)(ldsA + r * 256 + 32 * sg + 16)                         \
                = pack8(stash[4*half+2], stash[4*half+3]);                   \
        }                                                                    \
    }

#define SSTEP(HSRC, HDST, UVC, UVN, S_) {                                    \
        UVN = *(const _Float16*)(ubuf + ((((S_) + 1) & 63) << 9) + tid * 2); \
        float a0 = 0.f, a1 = 0.f, a2 = 0.f, a3 = 0.f;                        \
        _Pragma("unroll")                                                    \
        for (int i = 0; i < 8; ++i) {                                        \
            float4 hv = *(const float4*)(HSRC + roff[i]);                    \
            h2* hp = (h2*)&hv;                                               \
            _Pragma("unroll")                                                \
            for (int z = 0; z < 4; ++z) {                                    \
                a0 = dot2f(w[0][4*i+z], hp[z], a0);                          \
                a1 = dot2f(w[1][4*i+z], hp[z], a1);                          \
                a2 = dot2f(w[2][4*i+z], hp[z], a2);                          \
                a3 = dot2f(w[3][4*i+z], hp[z], a3);                          \
            }                                                                \
        }                                                                    \
        a0 = dpp_add4(a0); a1 = dpp_add4(a1);                                \
        a2 = dpp_add4(a2); a3 = dpp_add4(a3);                                \
        float v = (kc == 0) ? a0 : (kc == 1) ? a1 : (kc == 2) ? a2 : a3;     \
        const float hnew = fast_tanh(v + (float)UVC);                        \
        hlast = hnew;                                                        \
        *(_Float16*)(HDST + wr_off) = (_Float16)hnew;                        \
        __builtin_amdgcn_sched_barrier(0);                                   \
        asm volatile("s_waitcnt lgkmcnt(0)");                                \
        __builtin_amdgcn_s_barrier();                                        \
        __builtin_amdgcn_sched_barrier(0);                                   \
    }

    if (nc > 0) {
        PLOADS(TT - len2);                          // chunk 0 gather
        for (int c = 0; c < nc; ++c) {
            const int tbase = (TT - len2) + 64 * c;

            // ---- chunk GEMM: stash -> ldsA -> MFMA -> ubuf ----
            PWRITES;
            __syncthreads();

            f32x4 acc[4][4];                        // [rt][ct]
            #pragma unroll
            for (int rt = 0; rt < 4; ++rt)
                #pragma unroll
                for (int ct = 0; ct < 4; ++ct)
                    acc[rt][ct] = (f32x4){bias[ct], bias[ct], bias[ct], bias[ct]};

            #pragma unroll
            for (int kk = 0; kk < 4; ++kk) {
                const int ko = (32 * kk + 8 * quad) * 2;
                f16x8 af0 = *(const f16x8*)(ldsA + (l15)      * 256 + ko);
                f16x8 af1 = *(const f16x8*)(ldsA + (16 + l15) * 256 + ko);
                f16x8 af2 = *(const f16x8*)(ldsA + (32 + l15) * 256 + ko);
                f16x8 af3 = *(const f16x8*)(ldsA + (48 + l15) * 256 + ko);
                #pragma unroll
                for (int ct = 0; ct < 4; ++ct) {
                    acc[0][ct] = __builtin_amdgcn_mfma_f32_16x16x32_f16(af0, bfih[ct][kk], acc[0][ct], 0, 0, 0);
                    acc[1][ct] = __builtin_amdgcn_mfma_f32_16x16x32_f16(af1, bfih[ct][kk], acc[1][ct], 0, 0, 0);
                    acc[2][ct] = __builtin_amdgcn_mfma_f32_16x16x32_f16(af2, bfih[ct][kk], acc[2][ct], 0, 0, 0);
                    acc[3][ct] = __builtin_amdgcn_mfma_f32_16x16x32_f16(af3, bfih[ct][kk], acc[3][ct], 0, 0, 0);
                }
            }

            #pragma unroll
            for (int rt = 0; rt < 4; ++rt) {
                #pragma unroll
                for (int ct = 0; ct < 4; ++ct) {
                    const int chb = (64 * wv + 16 * ct + l15) * 2;
                    #pragma unroll
                    for (int rg = 0; rg < 4; ++rg) {
                        const int tok = 16 * rt + 4 * quad + rg;
                        const bool act = (tbase + tok) >= start;
                        const float dv = act ? acc[rt][ct][rg] : 0.f;
                        *(_Float16*)(ubuf + tok * 512 + chb) = (_Float16)dv;
                    }
                }
            }
            __syncthreads();

            // issue next chunk's gather NOW — flies under the scan (vmcnt
            // untouched by SBAR's lgkm-only wait)
            if (c + 1 < nc) { PLOADS(tbase + 64); }

            // ---- serial scan over this chunk (verified R14 SSTEP) ----
            const int steps = (len2 - c * 64 < 64) ? (len2 - c * 64) : 64;
            _Float16 uv0 = *(const _Float16*)(ubuf + tid * 2);
            _Float16 uv1;
            for (int s = 0; s < steps; s += 2) {
                SSTEP(hbufA, hbufB, uv0, uv1, s);       // even: A -> B
                SSTEP(hbufB, hbufA, uv1, uv0, s + 1);   // odd:  B -> A
            }
        }
    }

    // ---- fused MLP head + log_softmax (thread tid holds h[b][tid]) ----
    sh[tid] = hlast;
    __syncthreads();

    float acc[4];
    #pragma unroll
    for (int i = 0; i < 4; ++i) acc[i] = b0[tid + 256 * i];
    const float4* sh4 = (const float4*)sh;
    for (int k4 = 0; k4 < HH / 4; ++k4) {
        float4 hv = sh4[k4];
        #pragma unroll
        for (int i = 0; i < 4; ++i) {
            float4 wv4 = ((const float4*)(W0 + (size_t)(tid + 256 * i) * HH))[k4];
            acc[i] += wv4.x * hv.x + wv4.y * hv.y + wv4.z * hv.z + wv4.w * hv.w;
        }
    }
    #pragma unroll
    for (int i = 0; i < 4; ++i) sh1[tid + 256 * i] = fmaxf(acc[i], 0.f);
    __syncthreads();

    float pc[CC] = {0.f, 0.f, 0.f, 0.f, 0.f};
    for (int k = tid; k < MM; k += 256) {
        float hv = sh1[k];
        #pragma unroll
        for (int c = 0; c < CC; ++c) pc[c] += W1[(size_t)c * MM + k] * hv;
    }
    const int lane6 = tid & 63, wid = tid >> 6;
    #pragma unroll
    for (int c = 0; c < CC; ++c) {
        float v = pc[c];
        #pragma unroll
        for (int off = 32; off > 0; off >>= 1) v += __shfl_down(v, off, 64);
        if (lane6 == 0) sred[c][wid] = v;
    }
    __syncthreads();
    if (tid < CC) {
        float s = sred[tid][0] + sred[tid][1] + sred[tid][2] + sred[tid][3]
                + b1[tid];
        slog[tid] = fmaxf(s, 0.f);
    }
    __syncthreads();
    if (tid < CC) {
        float mx = slog[0];
        #pragma unroll
        for (int c = 1; c < CC; ++c) mx = fmaxf(mx, slog[c]);
        float se = 0.f;
        #pragma unroll
        for (int c = 0; c < CC; ++c) se += __expf(slog[c] - mx);
        out[(size_t)b * CC + tid] = slog[tid] - mx - __logf(se);
    }
}

// ---------------------------------------------------------------------------
extern "C" void kernel_launch(void* const* d_in, const int* in_sizes, int n_in,
                              void* d_out, int out_size, void* d_ws, size_t ws_size,
                              hipStream_t stream) {
    const int*   x       = (const int*)d_in[0];
    const int*   lengths = (const int*)d_in[1];
    const float* emb     = (const float*)d_in[2];
    const float* W_ih    = (const float*)d_in[3];
    const float* W_hh    = (const float*)d_in[4];
    const float* b_ih    = (const float*)d_in[5];
    const float* b_hh    = (const float*)d_in[6];
    const float* W0      = (const float*)d_in[7];
    const float* b0      = (const float*)d_in[8];
    const float* W1      = (const float*)d_in[9];
    const float* b1      = (const float*)d_in[10];
    float* out = (float*)d_out;

    // workspace unused (u eliminated)
    (void)d_ws; (void)ws_size;

    k_fused<<<BB, 256, 0, stream>>>(x, lengths, emb, W_ih, W_hh,
                                    b_ih, b_hh, W0, b0, W1, b1, out);
}